// Round 11
// baseline (253.565 us; speedup 1.0000x reference)
//
#include <hip/hip_runtime.h>
#include <hip/hip_bf16.h>

#define N_NODES  50000
#define N_EDGES  500000
#define DIM      128
#define N_GRAPHS 256

#define SCAN_B   512
#define SCAN_NB  ((N_NODES + SCAN_B - 1) / SCAN_B)   // 98

// prep_kernel block partition
#define PB_CVT   6250                      // x -> bf16: 1.6M float4 / 256
#define PB_W     32                        // weights -> packed bf16: 8192 thr
#define PB_DEG   ((N_NODES + 255) / 256)   // zero deg: 196
#define PB_POOL  128                       // zero pooled: 32768 f32 / 256
#define PB_TOTAL (PB_CVT + PB_W + PB_DEG + PB_POOL)

typedef __attribute__((ext_vector_type(8))) short bf16x8;
typedef __attribute__((ext_vector_type(4))) float f32x4;

__device__ __forceinline__ unsigned short f2bf(float f) {
    __hip_bfloat16 h = __float2bfloat16(f);          // RNE
    return *(unsigned short*)&h;
}
__device__ __forceinline__ float bflo(unsigned int v) { return __uint_as_float(v << 16); }
__device__ __forceinline__ float bfhi(unsigned int v) { return __uint_as_float(v & 0xffff0000u); }

// ===========================================================================
// Fused prep: x->bf16 | weights->packed bf16 | zero deg | zero pooled
// ===========================================================================
__global__ __launch_bounds__(256)
void prep_kernel(const float* __restrict__ x,
                 const float* __restrict__ W1_rel, const float* __restrict__ W1_root,
                 const float* __restrict__ W2_rel, const float* __restrict__ W2_root,
                 unsigned short* __restrict__ xb, unsigned short* __restrict__ Wb,
                 int* __restrict__ deg, float* __restrict__ pooled)
{
    int b = blockIdx.x, t = threadIdx.x;
    if (b < PB_CVT) {
        int i = b * 256 + t;
        float4 v = ((const float4*)x)[i];
        ushort4 o;
        o.x = f2bf(v.x); o.y = f2bf(v.y); o.z = f2bf(v.z); o.w = f2bf(v.w);
        ((ushort4*)xb)[i] = o;
    } else if (b < PB_CVT + PB_W) {
        int u = (b - PB_CVT) * 256 + t;      // 0..8191
        int layer = u >> 12;
        int kb    = (u >> 7) & 31;
        int col   = u & 127;
        int k0    = kb * 8;
        const float* Wrel  = layer ? W2_rel  : W1_rel;
        const float* Wroot = layer ? W2_root : W1_root;
        const float* srcp = (k0 < 128) ? (Wrel + col * 128 + k0)
                                       : (Wroot + col * 128 + (k0 - 128));
        float4 v0 = ((const float4*)srcp)[0];
        float4 v1 = ((const float4*)srcp)[1];
        ushort4 o0, o1;
        o0.x = f2bf(v0.x); o0.y = f2bf(v0.y); o0.z = f2bf(v0.z); o0.w = f2bf(v0.w);
        o1.x = f2bf(v1.x); o1.y = f2bf(v1.y); o1.z = f2bf(v1.z); o1.w = f2bf(v1.w);
        unsigned short* dst = Wb + (size_t)layer * 32768 + ((kb * 128 + col) * 8);
        ((ushort4*)dst)[0] = o0;
        ((ushort4*)dst)[1] = o1;
    } else if (b < PB_CVT + PB_W + PB_DEG) {
        int i = (b - PB_CVT - PB_W) * 256 + t;
        if (i < N_NODES) deg[i] = 0;
    } else {
        int i = (b - PB_CVT - PB_W - PB_DEG) * 256 + t;   // < 32768 exactly
        pooled[i] = 0.f;
    }
}

// ===========================================================================
// CSR build (edge list identical for both layers -> build once per call)
// ===========================================================================
__global__ void hist_kernel(const int* __restrict__ dst, int* __restrict__ deg)
{
    int e = blockIdx.x * blockDim.x + threadIdx.x;
    if (e < N_EDGES) atomicAdd(&deg[dst[e]], 1);
}

// ---- 3-phase device-wide exclusive scan ----
__global__ __launch_bounds__(SCAN_B)
void block_sum_kernel(const int* __restrict__ deg, int* __restrict__ bsum)
{
    __shared__ int red[SCAN_B];
    int t = threadIdx.x;
    int idx = blockIdx.x * SCAN_B + t;
    red[t] = (idx < N_NODES) ? deg[idx] : 0;
    __syncthreads();
    for (int off = SCAN_B / 2; off > 0; off >>= 1) {
        if (t < off) red[t] += red[t + off];
        __syncthreads();
    }
    if (t == 0) bsum[blockIdx.x] = red[0];
}

__global__ __launch_bounds__(128)
void scan_sums_kernel(int* __restrict__ bsum)   // in-place -> exclusive prefix
{
    __shared__ int s[128];
    int t = threadIdx.x;
    int v = (t < SCAN_NB) ? bsum[t] : 0;
    s[t] = v;
    __syncthreads();
    for (int off = 1; off < 128; off <<= 1) {
        int u = (t >= off) ? s[t - off] : 0;
        __syncthreads();
        s[t] += u;
        __syncthreads();
    }
    if (t < SCAN_NB) bsum[t] = s[t] - v;
}

__global__ __launch_bounds__(SCAN_B)
void scan_apply_kernel(const int* __restrict__ deg, const int* __restrict__ bsum,
                       int* __restrict__ row_ptr, int* __restrict__ cursor)
{
    __shared__ int s[SCAN_B];
    int t = threadIdx.x;
    int idx = blockIdx.x * SCAN_B + t;
    int v = (idx < N_NODES) ? deg[idx] : 0;
    s[t] = v;
    __syncthreads();
    for (int off = 1; off < SCAN_B; off <<= 1) {
        int u = (t >= off) ? s[t - off] : 0;
        __syncthreads();
        s[t] += u;
        __syncthreads();
    }
    if (idx < N_NODES) {
        int ex = bsum[blockIdx.x] + s[t] - v;
        row_ptr[idx] = ex;
        cursor[idx]  = ex;
    }
    if (idx == 0) row_ptr[N_NODES] = N_EDGES;
}

__global__ void build_kernel(const int* __restrict__ src, const int* __restrict__ dst,
                             int* __restrict__ cursor, int* __restrict__ edge_src)
{
    int e = blockIdx.x * blockDim.x + threadIdx.x;
    if (e < N_EDGES) {
        int pos = atomicAdd(&cursor[dst[e]], 1);
        edge_src[pos] = src[e];
    }
}

// ===========================================================================
// Gather-aggregate (bf16 feat -> bf16 agg, f32 accumulate in-register).
// One wave per node; half-wave per edge (lane holds 4 feats as uint2).
// At the L2/L3 random-row service floor (R8/R10 parallelism probes neutral).
// ===========================================================================
__global__ __launch_bounds__(256)
void gather_kernel(const unsigned short* __restrict__ feat,
                   const int* __restrict__ row_ptr,
                   const int* __restrict__ edge_src,
                   unsigned short* __restrict__ agg)
{
    int wid  = (blockIdx.x * blockDim.x + threadIdx.x) >> 6;
    int lane = threadIdx.x & 63;
    int node = __builtin_amdgcn_readfirstlane(wid);
    int half = lane >> 5;
    int l31  = lane & 31;

    const uint2* f = (const uint2*)feat;   // 4 bf16 per uint2; 32 per row
    int e  = row_ptr[node];
    int e1 = row_ptr[node + 1];

    float a0 = 0.f, a1 = 0.f, a2 = 0.f, a3 = 0.f;
    float b0 = 0.f, b1 = 0.f, b2 = 0.f, b3 = 0.f;

    for (; e + 7 < e1; e += 8) {
        int myi = edge_src[e + (lane & 7)];        // one 32B coalesced load
        int i0 = __shfl(myi, half * 4 + 0, 64);
        int i1 = __shfl(myi, half * 4 + 1, 64);
        int i2 = __shfl(myi, half * 4 + 2, 64);
        int i3 = __shfl(myi, half * 4 + 3, 64);
        uint2 v0 = f[i0 * 32 + l31];
        uint2 v1 = f[i1 * 32 + l31];
        uint2 v2 = f[i2 * 32 + l31];
        uint2 v3 = f[i3 * 32 + l31];
        a0 += bflo(v0.x); a1 += bfhi(v0.x); a2 += bflo(v0.y); a3 += bfhi(v0.y);
        b0 += bflo(v1.x); b1 += bfhi(v1.x); b2 += bflo(v1.y); b3 += bfhi(v1.y);
        a0 += bflo(v2.x); a1 += bfhi(v2.x); a2 += bflo(v2.y); a3 += bfhi(v2.y);
        b0 += bflo(v3.x); b1 += bfhi(v3.x); b2 += bflo(v3.y); b3 += bfhi(v3.y);
    }
    for (; e < e1; e += 2) {
        int my = e + half;
        if (my < e1) {
            uint2 v = f[edge_src[my] * 32 + l31];
            a0 += bflo(v.x); a1 += bfhi(v.x); a2 += bflo(v.y); a3 += bfhi(v.y);
        }
    }
    a0 += b0; a1 += b1; a2 += b2; a3 += b3;
    a0 += __shfl_xor(a0, 32, 64);
    a1 += __shfl_xor(a1, 32, 64);
    a2 += __shfl_xor(a2, 32, 64);
    a3 += __shfl_xor(a3, 32, 64);
    if (half == 0) {
        uint2 o;
        o.x = (unsigned)f2bf(a0) | ((unsigned)f2bf(a1) << 16);
        o.y = (unsigned)f2bf(a2) | ((unsigned)f2bf(a3) << 16);
        ((uint2*)agg)[node * 32 + l31] = o;
    }
}

// ===========================================================================
// MFMA GEMM, column-split:  block = 128 rows x 64 cols, 256 thr = 4 waves.
// blockIdx: rowblk = bx>>1, ch = bx&1 (cols ch*64..ch*64+63).
// Stages only its 32KB half of Wb -> 5 blocks/CU (20 waves/CU, 2.5x the
// occupancy of the 64KB variant; staging+A-latency now hidden).
// Wave: 2 row-tiles x 4 col-tiles; B-frag reads contiguous 1KB/wave.
// POOL: fused mean-pool numerator via run-compressed atomics (batch sorted).
// ===========================================================================
template <bool POOL>
__global__ __launch_bounds__(256)
void gemm_mfma(const unsigned short* __restrict__ Aagg,
               const unsigned short* __restrict__ Ax,
               const unsigned short* __restrict__ Wb,   // one layer: 64KB packed [kb][128][8]
               const float* __restrict__ bias,
               unsigned short* __restrict__ Hout,   // !POOL
               float* __restrict__ pooled,          // POOL
               const int* __restrict__ batch)       // POOL
{
    __shared__ __align__(16) unsigned short wlds[16384];  // 32KB: [kb][64 cols][8]

    const int t  = threadIdx.x;
    const int bx = blockIdx.x;
    const int rowblk = bx >> 1;
    const int ch     = bx & 1;        // column half

    // ---- stage this half's W: 2048 uint4, 8 iters x 256 thr ----
    {
        const uint4* s4 = (const uint4*)Wb;
        uint4* d4 = (uint4*)wlds;
#pragma unroll
        for (int i = 0; i < 8; ++i) {
            int j  = i * 256 + t;         // 0..2047
            int kb = j >> 6;              // 64 uint4 per kb-half-row
            int w  = j & 63;
            d4[j] = s4[kb * 128 + ch * 64 + w];
        }
    }
    __syncthreads();

    const int wave = t >> 6;
    const int lane = t & 63;
    const int q    = lane >> 4;                 // 0..3
    const int ln15 = lane & 15;
    const int m0   = rowblk * 128 + wave * 16;  // tile0 rows; tile1 = +64

    int r0 = m0 + ln15;      int r0c = r0 < N_NODES ? r0 : N_NODES - 1;
    int r1 = m0 + 64 + ln15; int r1c = r1 < N_NODES ? r1 : N_NODES - 1;

    const unsigned short* A00 = Aagg + (size_t)r0c * DIM + q * 8;  // k 0..127
    const unsigned short* A01 = Ax   + (size_t)r0c * DIM + q * 8;  // k 128..255
    const unsigned short* A10 = Aagg + (size_t)r1c * DIM + q * 8;
    const unsigned short* A11 = Ax   + (size_t)r1c * DIM + q * 8;

    f32x4 acc0[4], acc1[4];
#pragma unroll
    for (int ct = 0; ct < 4; ++ct) {
        acc0[ct] = (f32x4){0.f, 0.f, 0.f, 0.f};
        acc1[ct] = (f32x4){0.f, 0.f, 0.f, 0.f};
    }

#pragma unroll
    for (int ks = 0; ks < 8; ++ks) {
        bf16x8 a0 = *(const bf16x8*)((ks < 4) ? (A00 + ks * 32) : (A01 + (ks - 4) * 32));
        bf16x8 a1 = *(const bf16x8*)((ks < 4) ? (A10 + ks * 32) : (A11 + (ks - 4) * 32));
        const unsigned short* wrow = wlds + (ks * 4 + q) * 512;   // [kb][64][8]
#pragma unroll
        for (int ct = 0; ct < 4; ++ct) {
            bf16x8 bf = *(const bf16x8*)&wrow[(ct * 16 + ln15) * 8];
            acc0[ct] = __builtin_amdgcn_mfma_f32_16x16x32_bf16(a0, bf, acc0[ct], 0, 0, 0);
            acc1[ct] = __builtin_amdgcn_mfma_f32_16x16x32_bf16(a1, bf, acc1[ct], 0, 0, 0);
        }
    }

    float bj[4];
#pragma unroll
    for (int ct = 0; ct < 4; ++ct) bj[ct] = bias[ch * 64 + ct * 16 + ln15];

#pragma unroll
    for (int rt = 0; rt < 2; ++rt) {
        const f32x4* acc = rt ? acc1 : acc0;
        const int rb = m0 + rt * 64 + q * 4;   // 4 consecutive rows

        if (!POOL) {
#pragma unroll
            for (int ct = 0; ct < 4; ++ct) {
                int coln = ch * 64 + ct * 16 + ln15;
#pragma unroll
                for (int r = 0; r < 4; ++r) {
                    int row = rb + r;
                    if (row < N_NODES) {
                        float v = acc[ct][r] + bj[ct];
                        v = v > 0.f ? v : 0.f;
                        Hout[(size_t)row * DIM + coln] = f2bf(v);
                    }
                }
            }
        } else {
            int gg[4];
#pragma unroll
            for (int r = 0; r < 4; ++r) gg[r] = (rb + r < N_NODES) ? batch[rb + r] : -1;
            bool uni = (gg[0] == gg[3]) && (gg[3] >= 0);
#pragma unroll
            for (int ct = 0; ct < 4; ++ct) {
                int coln = ch * 64 + ct * 16 + ln15;
                float v[4];
#pragma unroll
                for (int r = 0; r < 4; ++r) {
                    float x = acc[ct][r] + bj[ct];
                    v[r] = x > 0.f ? x : 0.f;
                }
                if (uni) {
                    atomicAdd(&pooled[gg[0] * DIM + coln], v[0] + v[1] + v[2] + v[3]);
                } else {
#pragma unroll
                    for (int r = 0; r < 4; ++r)
                        if (gg[r] >= 0) atomicAdd(&pooled[gg[r] * DIM + coln], v[r]);
                }
            }
        }
    }
}

// ===========================================================================
// out[g] = (pooled_sum[g]·W_out) / max(cnt_g,1) + b_out.  (all f32)
// ===========================================================================
__global__ void finalize_kernel(const float* __restrict__ pooled, const int* __restrict__ batch,
                                const float* __restrict__ Wout, const float* __restrict__ bout,
                                float* __restrict__ out)
{
    int g = blockIdx.x;
    int lane = threadIdx.x;  // 0..63

    int lo0 = 0, hi0 = N_NODES;
    while (lo0 < hi0) { int m = (lo0 + hi0) >> 1; if (batch[m] < g) lo0 = m + 1; else hi0 = m; }
    int lo1 = lo0, hi1 = N_NODES;
    while (lo1 < hi1) { int m = (lo1 + hi1) >> 1; if (batch[m] < g + 1) lo1 = m + 1; else hi1 = m; }
    int cnt = lo1 - lo0;

    float s = pooled[g * DIM + lane]      * Wout[lane]
            + pooled[g * DIM + 64 + lane] * Wout[64 + lane];
#pragma unroll
    for (int off = 32; off > 0; off >>= 1) s += __shfl_xor(s, off, 64);
    if (lane == 0) {
        float c = (float)(cnt > 1 ? cnt : 1);
        out[g] = s / c + bout[0];
    }
}

extern "C" void kernel_launch(void* const* d_in, const int* in_sizes, int n_in,
                              void* d_out, int out_size, void* d_ws, size_t ws_size,
                              hipStream_t stream)
{
    const float* x       = (const float*)d_in[0];
    const int*   ei      = (const int*)d_in[1];   // [2][E]: row 0 = src, row 1 = dst
    const int*   batch   = (const int*)d_in[2];
    const float* W1_rel  = (const float*)d_in[3];
    const float* W1_root = (const float*)d_in[4];
    const float* b1      = (const float*)d_in[5];
    const float* W2_rel  = (const float*)d_in[6];
    const float* W2_root = (const float*)d_in[7];
    const float* b2      = (const float*)d_in[8];
    const float* W_out   = (const float*)d_in[9];
    const float* b_out   = (const float*)d_in[10];
    float* out = (float*)d_out;

    const int* src  = ei;
    const int* dstv = ei + N_EDGES;

    // Workspace layout (bytes):
    //   aggb (bf16) @ 0          : 12,800,000
    //   xb   (bf16) @ 12,800,000 : 12,800,000
    //   h1b  (bf16) @ 25,600,000 : 12,800,000
    //   pooled f32  @ 38,400,000 :    131,072
    //   deg         @ 38,531,072 :    200,000
    //   row_ptr     @ 38,731,072 :    200,004
    //   edge_src    @ 38,931,200 :  2,000,000
    //   cursor      @ 40,931,200 :    200,000
    //   bsum        @ 41,131,200 :        512
    //   Wb  (bf16)  @ 41,131,712 :    131,072   (~41.3 MB)
    char* ws = (char*)d_ws;
    unsigned short* aggb = (unsigned short*)ws;
    unsigned short* xb   = (unsigned short*)(ws + 12800000);
    unsigned short* h1b  = (unsigned short*)(ws + 25600000);
    float* pooled        = (float*)(ws + 38400000);
    int*   deg           = (int*)  (ws + 38531072);
    int*   row_ptr       = (int*)  (ws + 38731072);
    int*   edge_src      = (int*)  (ws + 38931200);
    int*   cursor        = (int*)  (ws + 40931200);
    int*   bsum          = (int*)  (ws + 41131200);
    unsigned short* Wb   = (unsigned short*)(ws + 41131712);

    // ---- fused prep + CSR build ----
    prep_kernel      <<<PB_TOTAL, 256, 0, stream>>>(x, W1_rel, W1_root, W2_rel, W2_root,
                                                    xb, Wb, deg, pooled);
    hist_kernel      <<<(N_EDGES + 255) / 256, 256, 0, stream>>>(dstv, deg);
    block_sum_kernel <<<SCAN_NB, SCAN_B, 0, stream>>>(deg, bsum);
    scan_sums_kernel <<<1, 128, 0, stream>>>(bsum);
    scan_apply_kernel<<<SCAN_NB, SCAN_B, 0, stream>>>(deg, bsum, row_ptr, cursor);
    build_kernel     <<<(N_EDGES + 255) / 256, 256, 0, stream>>>(src, dstv, cursor, edge_src);

    const int gemm_grid = 2 * ((N_NODES + 127) / 128);   // 782 (row-blk x col-half)

    // ---- Layer 1 ----
    gather_kernel<<<N_NODES / 4, 256, 0, stream>>>(xb, row_ptr, edge_src, aggb);
    gemm_mfma<false><<<gemm_grid, 256, 0, stream>>>(
        aggb, xb, Wb, b1, h1b, nullptr, nullptr);

    // ---- Layer 2 (+ fused mean-pool numerator) ----
    gather_kernel<<<N_NODES / 4, 256, 0, stream>>>(h1b, row_ptr, edge_src, aggb);
    gemm_mfma<true><<<gemm_grid, 256, 0, stream>>>(
        aggb, h1b, Wb + 32768, b2, nullptr, pooled, batch);

    // ---- Output head ----
    finalize_kernel<<<N_GRAPHS, 64, 0, stream>>>(pooled, batch, W_out, b_out, out);
}

// Round 12
// 240.902 us; speedup vs baseline: 1.0526x; 1.0526x over previous
//
#include <hip/hip_runtime.h>
#include <hip/hip_bf16.h>

#define N_NODES  50000
#define N_EDGES  500000
#define DIM      128
#define N_GRAPHS 256

#define SCAN_B   512
#define SCAN_NB  ((N_NODES + SCAN_B - 1) / SCAN_B)   // 98

// prep_kernel block partition
#define PB_CVT   6250                      // x -> bf16: 1.6M float4 / 256
#define PB_W     32                        // weights -> packed bf16: 8192 thr
#define PB_DEG   ((N_NODES + 255) / 256)   // zero deg: 196
#define PB_POOL  128                       // zero pooled: 32768 f32 / 256
#define PB_TOTAL (PB_CVT + PB_W + PB_DEG + PB_POOL)

typedef __attribute__((ext_vector_type(8))) short bf16x8;
typedef __attribute__((ext_vector_type(4))) float f32x4;

__device__ __forceinline__ unsigned short f2bf(float f) {
    __hip_bfloat16 h = __float2bfloat16(f);          // RNE
    return *(unsigned short*)&h;
}
__device__ __forceinline__ float bflo(unsigned int v) { return __uint_as_float(v << 16); }
__device__ __forceinline__ float bfhi(unsigned int v) { return __uint_as_float(v & 0xffff0000u); }

// ===========================================================================
// Fused prep: x->bf16 | weights->packed bf16 | zero deg | zero pooled
// ===========================================================================
__global__ __launch_bounds__(256)
void prep_kernel(const float* __restrict__ x,
                 const float* __restrict__ W1_rel, const float* __restrict__ W1_root,
                 const float* __restrict__ W2_rel, const float* __restrict__ W2_root,
                 unsigned short* __restrict__ xb, unsigned short* __restrict__ Wb,
                 int* __restrict__ deg, float* __restrict__ pooled)
{
    int b = blockIdx.x, t = threadIdx.x;
    if (b < PB_CVT) {
        int i = b * 256 + t;
        float4 v = ((const float4*)x)[i];
        ushort4 o;
        o.x = f2bf(v.x); o.y = f2bf(v.y); o.z = f2bf(v.z); o.w = f2bf(v.w);
        ((ushort4*)xb)[i] = o;
    } else if (b < PB_CVT + PB_W) {
        int u = (b - PB_CVT) * 256 + t;      // 0..8191
        int layer = u >> 12;
        int kb    = (u >> 7) & 31;
        int col   = u & 127;
        int k0    = kb * 8;
        const float* Wrel  = layer ? W2_rel  : W1_rel;
        const float* Wroot = layer ? W2_root : W1_root;
        const float* srcp = (k0 < 128) ? (Wrel + col * 128 + k0)
                                       : (Wroot + col * 128 + (k0 - 128));
        float4 v0 = ((const float4*)srcp)[0];
        float4 v1 = ((const float4*)srcp)[1];
        ushort4 o0, o1;
        o0.x = f2bf(v0.x); o0.y = f2bf(v0.y); o0.z = f2bf(v0.z); o0.w = f2bf(v0.w);
        o1.x = f2bf(v1.x); o1.y = f2bf(v1.y); o1.z = f2bf(v1.z); o1.w = f2bf(v1.w);
        unsigned short* dst = Wb + (size_t)layer * 32768 + ((kb * 128 + col) * 8);
        ((ushort4*)dst)[0] = o0;
        ((ushort4*)dst)[1] = o1;
    } else if (b < PB_CVT + PB_W + PB_DEG) {
        int i = (b - PB_CVT - PB_W) * 256 + t;
        if (i < N_NODES) deg[i] = 0;
    } else {
        int i = (b - PB_CVT - PB_W - PB_DEG) * 256 + t;   // < 32768 exactly
        pooled[i] = 0.f;
    }
}

// ===========================================================================
// CSR build (edge list identical for both layers -> build once per call)
// ===========================================================================
__global__ void hist_kernel(const int* __restrict__ dst, int* __restrict__ deg)
{
    int e = blockIdx.x * blockDim.x + threadIdx.x;
    if (e < N_EDGES) atomicAdd(&deg[dst[e]], 1);
}

// ---- 3-phase device-wide exclusive scan (best of 1-block/3-phase/chained) ----
__global__ __launch_bounds__(SCAN_B)
void block_sum_kernel(const int* __restrict__ deg, int* __restrict__ bsum)
{
    __shared__ int red[SCAN_B];
    int t = threadIdx.x;
    int idx = blockIdx.x * SCAN_B + t;
    red[t] = (idx < N_NODES) ? deg[idx] : 0;
    __syncthreads();
    for (int off = SCAN_B / 2; off > 0; off >>= 1) {
        if (t < off) red[t] += red[t + off];
        __syncthreads();
    }
    if (t == 0) bsum[blockIdx.x] = red[0];
}

__global__ __launch_bounds__(128)
void scan_sums_kernel(int* __restrict__ bsum)   // in-place -> exclusive prefix
{
    __shared__ int s[128];
    int t = threadIdx.x;
    int v = (t < SCAN_NB) ? bsum[t] : 0;
    s[t] = v;
    __syncthreads();
    for (int off = 1; off < 128; off <<= 1) {
        int u = (t >= off) ? s[t - off] : 0;
        __syncthreads();
        s[t] += u;
        __syncthreads();
    }
    if (t < SCAN_NB) bsum[t] = s[t] - v;
}

__global__ __launch_bounds__(SCAN_B)
void scan_apply_kernel(const int* __restrict__ deg, const int* __restrict__ bsum,
                       int* __restrict__ row_ptr, int* __restrict__ cursor)
{
    __shared__ int s[SCAN_B];
    int t = threadIdx.x;
    int idx = blockIdx.x * SCAN_B + t;
    int v = (idx < N_NODES) ? deg[idx] : 0;
    s[t] = v;
    __syncthreads();
    for (int off = 1; off < SCAN_B; off <<= 1) {
        int u = (t >= off) ? s[t - off] : 0;
        __syncthreads();
        s[t] += u;
        __syncthreads();
    }
    if (idx < N_NODES) {
        int ex = bsum[blockIdx.x] + s[t] - v;
        row_ptr[idx] = ex;
        cursor[idx]  = ex;
    }
    if (idx == 0) row_ptr[N_NODES] = N_EDGES;
}

__global__ void build_kernel(const int* __restrict__ src, const int* __restrict__ dst,
                             int* __restrict__ cursor, int* __restrict__ edge_src)
{
    int e = blockIdx.x * blockDim.x + threadIdx.x;
    if (e < N_EDGES) {
        int pos = atomicAdd(&cursor[dst[e]], 1);
        edge_src[pos] = src[e];
    }
}

// ===========================================================================
// Gather-aggregate (bf16 feat -> bf16 agg, f32 accumulate in-register).
// One wave per node; half-wave per edge (lane holds 4 feats as uint2).
// At the L2/L3 random-row service floor (R8/R10 parallelism probes neutral).
// ===========================================================================
__global__ __launch_bounds__(256)
void gather_kernel(const unsigned short* __restrict__ feat,
                   const int* __restrict__ row_ptr,
                   const int* __restrict__ edge_src,
                   unsigned short* __restrict__ agg)
{
    int wid  = (blockIdx.x * blockDim.x + threadIdx.x) >> 6;
    int lane = threadIdx.x & 63;
    int node = __builtin_amdgcn_readfirstlane(wid);
    int half = lane >> 5;
    int l31  = lane & 31;

    const uint2* f = (const uint2*)feat;   // 4 bf16 per uint2; 32 per row
    int e  = row_ptr[node];
    int e1 = row_ptr[node + 1];

    float a0 = 0.f, a1 = 0.f, a2 = 0.f, a3 = 0.f;
    float b0 = 0.f, b1 = 0.f, b2 = 0.f, b3 = 0.f;

    for (; e + 7 < e1; e += 8) {
        int myi = edge_src[e + (lane & 7)];        // one 32B coalesced load
        int i0 = __shfl(myi, half * 4 + 0, 64);
        int i1 = __shfl(myi, half * 4 + 1, 64);
        int i2 = __shfl(myi, half * 4 + 2, 64);
        int i3 = __shfl(myi, half * 4 + 3, 64);
        uint2 v0 = f[i0 * 32 + l31];
        uint2 v1 = f[i1 * 32 + l31];
        uint2 v2 = f[i2 * 32 + l31];
        uint2 v3 = f[i3 * 32 + l31];
        a0 += bflo(v0.x); a1 += bfhi(v0.x); a2 += bflo(v0.y); a3 += bfhi(v0.y);
        b0 += bflo(v1.x); b1 += bfhi(v1.x); b2 += bflo(v1.y); b3 += bfhi(v1.y);
        a0 += bflo(v2.x); a1 += bfhi(v2.x); a2 += bflo(v2.y); a3 += bfhi(v2.y);
        b0 += bflo(v3.x); b1 += bfhi(v3.x); b2 += bflo(v3.y); b3 += bfhi(v3.y);
    }
    for (; e < e1; e += 2) {
        int my = e + half;
        if (my < e1) {
            uint2 v = f[edge_src[my] * 32 + l31];
            a0 += bflo(v.x); a1 += bfhi(v.x); a2 += bflo(v.y); a3 += bfhi(v.y);
        }
    }
    a0 += b0; a1 += b1; a2 += b2; a3 += b3;
    a0 += __shfl_xor(a0, 32, 64);
    a1 += __shfl_xor(a1, 32, 64);
    a2 += __shfl_xor(a2, 32, 64);
    a3 += __shfl_xor(a3, 32, 64);
    if (half == 0) {
        uint2 o;
        o.x = (unsigned)f2bf(a0) | ((unsigned)f2bf(a1) << 16);
        o.y = (unsigned)f2bf(a2) | ((unsigned)f2bf(a3) << 16);
        ((uint2*)agg)[node * 32 + l31] = o;
    }
}

// ===========================================================================
// MFMA GEMM:  H[n][j] = relu( [agg|x][n,0:256] . W[j,0:256] + b[j] )
// Block = 256 thr = 4 waves, 128 rows per block (wave: 2 row-tiles of 16).
// W staged as a straight 64KB memcpy from pre-packed bf16 Wb into LDS
// [kb][col][8] -- B-frag reads are contiguous 1KB/wave (conflict-free).
// Best of three probed structures: no-LDS (+6us) and col-split (+6us) regress.
// POOL: fused mean-pool numerator via run-compressed atomics (batch sorted).
// ===========================================================================
template <bool POOL>
__global__ __launch_bounds__(256)
void gemm_mfma(const unsigned short* __restrict__ Aagg,
               const unsigned short* __restrict__ Ax,
               const unsigned short* __restrict__ Wb,   // one layer: 64KB
               const float* __restrict__ bias,
               unsigned short* __restrict__ Hout,   // !POOL
               float* __restrict__ pooled,          // POOL
               const int* __restrict__ batch)       // POOL
{
    __shared__ __align__(16) unsigned short wlds[32768];  // 64KB, [kb][col][8]

    const int t = threadIdx.x;

    {
        const uint4* s4 = (const uint4*)Wb;
        uint4* d4 = (uint4*)wlds;
#pragma unroll
        for (int i = 0; i < 16; ++i) d4[t + i * 256] = s4[t + i * 256];
    }
    __syncthreads();

    const int wave = t >> 6;
    const int lane = t & 63;
    const int q    = lane >> 4;                 // 0..3
    const int ln15 = lane & 15;
    const int m0   = blockIdx.x * 128 + wave * 16;   // tile0 rows; tile1 = +64

    int r0 = m0 + ln15;      int r0c = r0 < N_NODES ? r0 : N_NODES - 1;
    int r1 = m0 + 64 + ln15; int r1c = r1 < N_NODES ? r1 : N_NODES - 1;

    const unsigned short* A00 = Aagg + (size_t)r0c * DIM + q * 8;  // k 0..127
    const unsigned short* A01 = Ax   + (size_t)r0c * DIM + q * 8;  // k 128..255
    const unsigned short* A10 = Aagg + (size_t)r1c * DIM + q * 8;
    const unsigned short* A11 = Ax   + (size_t)r1c * DIM + q * 8;

    f32x4 acc0[8], acc1[8];
#pragma unroll
    for (int ct = 0; ct < 8; ++ct) {
        acc0[ct] = (f32x4){0.f, 0.f, 0.f, 0.f};
        acc1[ct] = (f32x4){0.f, 0.f, 0.f, 0.f};
    }

#pragma unroll
    for (int ks = 0; ks < 8; ++ks) {
        bf16x8 a0 = *(const bf16x8*)((ks < 4) ? (A00 + ks * 32) : (A01 + (ks - 4) * 32));
        bf16x8 a1 = *(const bf16x8*)((ks < 4) ? (A10 + ks * 32) : (A11 + (ks - 4) * 32));
        const unsigned short* wrow = wlds + (ks * 4 + q) * 1024;   // [kb][128][8]
#pragma unroll
        for (int ct = 0; ct < 8; ++ct) {
            bf16x8 bf = *(const bf16x8*)&wrow[(ct * 16 + ln15) * 8];
            acc0[ct] = __builtin_amdgcn_mfma_f32_16x16x32_bf16(a0, bf, acc0[ct], 0, 0, 0);
            acc1[ct] = __builtin_amdgcn_mfma_f32_16x16x32_bf16(a1, bf, acc1[ct], 0, 0, 0);
        }
    }

    float bj[8];
#pragma unroll
    for (int ct = 0; ct < 8; ++ct) bj[ct] = bias[ct * 16 + ln15];

#pragma unroll
    for (int rt = 0; rt < 2; ++rt) {
        const f32x4* acc = rt ? acc1 : acc0;
        const int rb = m0 + rt * 64 + q * 4;   // 4 consecutive rows

        if (!POOL) {
#pragma unroll
            for (int ct = 0; ct < 8; ++ct) {
                int coln = ct * 16 + ln15;
#pragma unroll
                for (int r = 0; r < 4; ++r) {
                    int row = rb + r;
                    if (row < N_NODES) {
                        float v = acc[ct][r] + bj[ct];
                        v = v > 0.f ? v : 0.f;
                        Hout[(size_t)row * DIM + coln] = f2bf(v);
                    }
                }
            }
        } else {
            int gg[4];
#pragma unroll
            for (int r = 0; r < 4; ++r) gg[r] = (rb + r < N_NODES) ? batch[rb + r] : -1;
            bool uni = (gg[0] == gg[3]) && (gg[3] >= 0);
#pragma unroll
            for (int ct = 0; ct < 8; ++ct) {
                int coln = ct * 16 + ln15;
                float v[4];
#pragma unroll
                for (int r = 0; r < 4; ++r) {
                    float x = acc[ct][r] + bj[ct];
                    v[r] = x > 0.f ? x : 0.f;
                }
                if (uni) {
                    atomicAdd(&pooled[gg[0] * DIM + coln], v[0] + v[1] + v[2] + v[3]);
                } else {
#pragma unroll
                    for (int r = 0; r < 4; ++r)
                        if (gg[r] >= 0) atomicAdd(&pooled[gg[r] * DIM + coln], v[r]);
                }
            }
        }
    }
}

// ===========================================================================
// out[g] = (pooled_sum[g]·W_out) / max(cnt_g,1) + b_out.  (all f32)
// ===========================================================================
__global__ void finalize_kernel(const float* __restrict__ pooled, const int* __restrict__ batch,
                                const float* __restrict__ Wout, const float* __restrict__ bout,
                                float* __restrict__ out)
{
    int g = blockIdx.x;
    int lane = threadIdx.x;  // 0..63

    int lo0 = 0, hi0 = N_NODES;
    while (lo0 < hi0) { int m = (lo0 + hi0) >> 1; if (batch[m] < g) lo0 = m + 1; else hi0 = m; }
    int lo1 = lo0, hi1 = N_NODES;
    while (lo1 < hi1) { int m = (lo1 + hi1) >> 1; if (batch[m] < g + 1) lo1 = m + 1; else hi1 = m; }
    int cnt = lo1 - lo0;

    float s = pooled[g * DIM + lane]      * Wout[lane]
            + pooled[g * DIM + 64 + lane] * Wout[64 + lane];
#pragma unroll
    for (int off = 32; off > 0; off >>= 1) s += __shfl_xor(s, off, 64);
    if (lane == 0) {
        float c = (float)(cnt > 1 ? cnt : 1);
        out[g] = s / c + bout[0];
    }
}

extern "C" void kernel_launch(void* const* d_in, const int* in_sizes, int n_in,
                              void* d_out, int out_size, void* d_ws, size_t ws_size,
                              hipStream_t stream)
{
    const float* x       = (const float*)d_in[0];
    const int*   ei      = (const int*)d_in[1];   // [2][E]: row 0 = src, row 1 = dst
    const int*   batch   = (const int*)d_in[2];
    const float* W1_rel  = (const float*)d_in[3];
    const float* W1_root = (const float*)d_in[4];
    const float* b1      = (const float*)d_in[5];
    const float* W2_rel  = (const float*)d_in[6];
    const float* W2_root = (const float*)d_in[7];
    const float* b2      = (const float*)d_in[8];
    const float* W_out   = (const float*)d_in[9];
    const float* b_out   = (const float*)d_in[10];
    float* out = (float*)d_out;

    const int* src  = ei;
    const int* dstv = ei + N_EDGES;

    // Workspace layout (bytes):
    //   aggb (bf16) @ 0          : 12,800,000
    //   xb   (bf16) @ 12,800,000 : 12,800,000
    //   h1b  (bf16) @ 25,600,000 : 12,800,000
    //   pooled f32  @ 38,400,000 :    131,072
    //   deg         @ 38,531,072 :    200,000
    //   row_ptr     @ 38,731,072 :    200,004
    //   edge_src    @ 38,931,200 :  2,000,000
    //   cursor      @ 40,931,200 :    200,000
    //   bsum        @ 41,131,200 :        512
    //   Wb  (bf16)  @ 41,131,712 :    131,072   (~41.3 MB)
    char* ws = (char*)d_ws;
    unsigned short* aggb = (unsigned short*)ws;
    unsigned short* xb   = (unsigned short*)(ws + 12800000);
    unsigned short* h1b  = (unsigned short*)(ws + 25600000);
    float* pooled        = (float*)(ws + 38400000);
    int*   deg           = (int*)  (ws + 38531072);
    int*   row_ptr       = (int*)  (ws + 38731072);
    int*   edge_src      = (int*)  (ws + 38931200);
    int*   cursor        = (int*)  (ws + 40931200);
    int*   bsum          = (int*)  (ws + 41131200);
    unsigned short* Wb   = (unsigned short*)(ws + 41131712);

    // ---- fused prep + CSR build ----
    prep_kernel      <<<PB_TOTAL, 256, 0, stream>>>(x, W1_rel, W1_root, W2_rel, W2_root,
                                                    xb, Wb, deg, pooled);
    hist_kernel      <<<(N_EDGES + 255) / 256, 256, 0, stream>>>(dstv, deg);
    block_sum_kernel <<<SCAN_NB, SCAN_B, 0, stream>>>(deg, bsum);
    scan_sums_kernel <<<1, 128, 0, stream>>>(bsum);
    scan_apply_kernel<<<SCAN_NB, SCAN_B, 0, stream>>>(deg, bsum, row_ptr, cursor);
    build_kernel     <<<(N_EDGES + 255) / 256, 256, 0, stream>>>(src, dstv, cursor, edge_src);

    const int gemm_grid = (N_NODES + 127) / 128;   // 391

    // ---- Layer 1 ----
    gather_kernel<<<N_NODES / 4, 256, 0, stream>>>(xb, row_ptr, edge_src, aggb);
    gemm_mfma<false><<<gemm_grid, 256, 0, stream>>>(
        aggb, xb, Wb, b1, h1b, nullptr, nullptr);

    // ---- Layer 2 (+ fused mean-pool numerator) ----
    gather_kernel<<<N_NODES / 4, 256, 0, stream>>>(h1b, row_ptr, edge_src, aggb);
    gemm_mfma<true><<<gemm_grid, 256, 0, stream>>>(
        aggb, h1b, Wb + 32768, b2, nullptr, pooled, batch);

    // ---- Output head ----
    finalize_kernel<<<N_GRAPHS, 64, 0, stream>>>(pooled, batch, W_out, b_out, out);
}